// Round 1
// baseline (409.173 us; speedup 1.0000x reference)
//
#include <hip/hip_runtime.h>
#include <cmath>

typedef unsigned short u16;
typedef unsigned short u16x8 __attribute__((ext_vector_type(8)));
typedef __bf16 bf16x8 __attribute__((ext_vector_type(8)));
typedef float f32x4 __attribute__((ext_vector_type(4)));

#define HNUM 8
#define HDIM 64
#define BATCH 4
#define NSEQ 2048
#define DMODEL 512

__device__ __forceinline__ u16 f2bf(float f) {
  unsigned int u = __builtin_bit_cast(unsigned int, f);
  u += 0x7fffu + ((u >> 16) & 1u);          // round-to-nearest-even
  return (u16)(u >> 16);
}

__device__ __forceinline__ f32x4 mfma_bf16(u16x8 a, u16x8 b, f32x4 c) {
  return __builtin_amdgcn_mfma_f32_16x16x32_bf16(
      __builtin_bit_cast(bf16x8, a), __builtin_bit_cast(bf16x8, b), c, 0, 0, 0);
}

// ---------------------------------------------------------------------------
// Bias table: tab[h][d] = in_band(bucket(d),h) ? pos_bias[bucket(d)][h] : -100
// Double-precision log so the integer bucket matches the numpy reference.
// ---------------------------------------------------------------------------
__global__ __launch_bounds__(256) void bias_tab_kernel(
    const float* __restrict__ pos_bias, float* __restrict__ tab) {
  int d = blockIdx.x * 256 + threadIdx.x;   // 0..2047
  if (d >= NSEQ) return;
  int bkt;
  if (d < 28) {
    bkt = d;
  } else {
    double t = log((double)d / 28.0) / log(2048.0 / 28.0) * 16.0;
    int ti = 28 + (int)t;                   // truncation == astype(int32), t>=0
    bkt = ti < 43 ? ti : 43;
  }
  const int lo[8] = {38, 34, 28, 20, 13, 7, 3, 0};
  const int hi[8] = {44, 40, 35, 28, 21, 14, 9, 6};
  #pragma unroll
  for (int h = 0; h < HNUM; ++h) {
    bool inb = (bkt >= lo[h]) && (bkt < hi[h]);
    tab[h * NSEQ + d] = inb ? pos_bias[bkt * HNUM + h] : -100.0f;
  }
}

// ---------------------------------------------------------------------------
// Generic bf16-MFMA GEMM: C[M,NCOLS] = A[M,512] @ W[512,NCOLS] + bias
// STAGE: 0 = A as-is, 1 = A * A2 (gated)
// EPI:   0 = pack q/k/v bf16 (+k_delta/+v_delta), 1 = sigmoid->fp32, 2 = fp32
// Tile 64x64, BK=32, 256 threads (4 waves, each 16 rows x 64 cols).
// ---------------------------------------------------------------------------
template <int NCOLS, int STAGE, int EPI>
__global__ __launch_bounds__(256) void gemm_kernel(
    const float* __restrict__ A, const float* __restrict__ A2,
    const float* __restrict__ W, const float* __restrict__ bias,
    const float* __restrict__ kdelta, const float* __restrict__ vdelta,
    u16* __restrict__ qbf, u16* __restrict__ kbf, u16* __restrict__ vbf,
    float* __restrict__ outp) {
  __shared__ u16 As[64][32];   // [m][k] bf16
  __shared__ u16 Ws[64][32];   // [n][k] bf16 (transposed)

  const int m0 = blockIdx.y * 64;
  const int n0 = blockIdx.x * 64;
  const int tid = threadIdx.x;
  const int w = tid >> 6, l = tid & 63, li = l & 15, lg = l >> 4;

  f32x4 acc[4] = {{0.f,0.f,0.f,0.f},{0.f,0.f,0.f,0.f},
                  {0.f,0.f,0.f,0.f},{0.f,0.f,0.f,0.f}};

  const int ar = tid >> 2;            // 0..63  (A row)
  const int ac = (tid & 3) << 3;      // 0,8,16,24 (A k)
  const int wk = tid >> 3;            // 0..31  (W k)
  const int wn = (tid & 7) << 3;      // 0..56  (W col)

  for (int kt = 0; kt < DMODEL / 32; ++kt) {
    // --- stage A (fp32 -> bf16) ---
    const float* ap = A + (size_t)(m0 + ar) * DMODEL + kt * 32 + ac;
    float4 f0 = *(const float4*)ap;
    float4 f1 = *(const float4*)(ap + 4);
    if constexpr (STAGE == 1) {
      const float* gp = A2 + (size_t)(m0 + ar) * DMODEL + kt * 32 + ac;
      float4 g0 = *(const float4*)gp;
      float4 g1 = *(const float4*)(gp + 4);
      f0.x *= g0.x; f0.y *= g0.y; f0.z *= g0.z; f0.w *= g0.w;
      f1.x *= g1.x; f1.y *= g1.y; f1.z *= g1.z; f1.w *= g1.w;
    }
    u16x8 pk;
    pk[0] = f2bf(f0.x); pk[1] = f2bf(f0.y); pk[2] = f2bf(f0.z); pk[3] = f2bf(f0.w);
    pk[4] = f2bf(f1.x); pk[5] = f2bf(f1.y); pk[6] = f2bf(f1.z); pk[7] = f2bf(f1.w);
    *(u16x8*)&As[ar][ac] = pk;

    // --- stage W transposed (fp32 -> bf16) ---
    const float* wp = W + (size_t)(kt * 32 + wk) * NCOLS + n0 + wn;
    float4 w0 = *(const float4*)wp;
    float4 w1 = *(const float4*)(wp + 4);
    Ws[wn + 0][wk] = f2bf(w0.x); Ws[wn + 1][wk] = f2bf(w0.y);
    Ws[wn + 2][wk] = f2bf(w0.z); Ws[wn + 3][wk] = f2bf(w0.w);
    Ws[wn + 4][wk] = f2bf(w1.x); Ws[wn + 5][wk] = f2bf(w1.y);
    Ws[wn + 6][wk] = f2bf(w1.z); Ws[wn + 7][wk] = f2bf(w1.w);
    __syncthreads();

    // --- MFMA: wave w owns rows [w*16, w*16+16), 4 col-tiles ---
    u16x8 af = *(const u16x8*)&As[w * 16 + li][lg * 8];
    #pragma unroll
    for (int ct = 0; ct < 4; ++ct) {
      u16x8 bfv = *(const u16x8*)&Ws[ct * 16 + li][lg * 8];
      acc[ct] = mfma_bf16(af, bfv, acc[ct]);
    }
    __syncthreads();
  }

  // --- epilogue.  C/D layout: col = li, row = lg*4 + reg ---
  #pragma unroll
  for (int ct = 0; ct < 4; ++ct) {
    int colg = n0 + ct * 16 + li;
    #pragma unroll
    for (int reg = 0; reg < 4; ++reg) {
      int rowg = m0 + w * 16 + lg * 4 + reg;
      float val = acc[ct][reg] + bias[colg];
      if constexpr (EPI == 0) {
        int which = colg >> 9;           // 0=q 1=k 2=v
        int inner = colg & 511;
        int hh = inner >> 6, hd = inner & 63;
        int bb = rowg >> 11, nn = rowg & 2047;
        size_t idx = (((size_t)bb * HNUM + hh) * NSEQ + nn) * HDIM + hd;
        if (which == 0)      qbf[idx] = f2bf(val);
        else if (which == 1) kbf[idx] = f2bf(val + kdelta[idx]);
        else                 vbf[idx] = f2bf(val + vdelta[idx]);
      } else if constexpr (EPI == 1) {
        outp[(size_t)rowg * NCOLS + colg] = 1.f / (1.f + __expf(-val));
      } else {
        outp[(size_t)rowg * NCOLS + colg] = val;
      }
    }
  }
}

// ---------------------------------------------------------------------------
// Flash attention with banded relative bias.
// Block = 64 q-rows (4 waves x 16), KV tiles of 32. 1024 blocks.
// ---------------------------------------------------------------------------
__global__ __launch_bounds__(256) void attn_kernel(
    const u16* __restrict__ qbf, const u16* __restrict__ kbf,
    const u16* __restrict__ vbf, const float* __restrict__ bias_tab,
    const float* __restrict__ if_gain, float* __restrict__ attn_out) {
  __shared__ u16 Ks[32][64];        // [kv][hd]
  __shared__ u16 Vt[64][32];        // [hd][kv]
  __shared__ u16 Plds[4][16][32];   // per-wave P

  const int qt = blockIdx.x & 31;
  const int bh = blockIdx.x >> 5;
  const int h = bh & 7;
  const int b = bh >> 3;
  const int q0 = qt * 64;
  const int tid = threadIdx.x;
  const int w = tid >> 6, l = tid & 63, li = l & 15, lg = l >> 4;

  // Q fragments held in registers for the whole KV loop
  const u16* qrow = qbf + ((size_t)bh * NSEQ + q0 + w * 16 + li) * HDIM;
  u16x8 qf0 = *(const u16x8*)(qrow + lg * 8);
  u16x8 qf1 = *(const u16x8*)(qrow + 32 + lg * 8);

  float mrun[4] = {-INFINITY, -INFINITY, -INFINITY, -INFINITY};
  float lrun[4] = {0.f, 0.f, 0.f, 0.f};
  f32x4 O[4] = {{0.f,0.f,0.f,0.f},{0.f,0.f,0.f,0.f},
                {0.f,0.f,0.f,0.f},{0.f,0.f,0.f,0.f}};

  const int sr = tid >> 3;          // 0..31 (kv row for staging)
  const int sc = (tid & 7) << 3;    // 0..56 (hd col for staging)
  const float* btab = bias_tab + h * NSEQ;

  for (int kv0 = 0; kv0 < q0 + 64; kv0 += 32) {
    // --- stage K tile and transposed V tile ---
    const size_t kvbase = ((size_t)bh * NSEQ + kv0 + sr) * HDIM + sc;
    *(u16x8*)&Ks[sr][sc] = *(const u16x8*)(kbf + kvbase);
    u16x8 vv = *(const u16x8*)(vbf + kvbase);
    #pragma unroll
    for (int j = 0; j < 8; ++j) Vt[sc + j][sr] = vv[j];
    __syncthreads();

    // --- S = Q K^T  (two 16-col tiles, K-dim = 64 = 2 MFMA steps) ---
    f32x4 s[2];
    #pragma unroll
    for (int t = 0; t < 2; ++t) {
      f32x4 a = {0.f, 0.f, 0.f, 0.f};
      u16x8 b0 = *(const u16x8*)&Ks[t * 16 + li][lg * 8];
      u16x8 b1 = *(const u16x8*)&Ks[t * 16 + li][32 + lg * 8];
      a = mfma_bf16(qf0, b0, a);
      a = mfma_bf16(qf1, b1, a);
      s[t] = a;
    }

    // --- scale + bias + causal mask + online softmax ---
    float fac[4];
    #pragma unroll
    for (int reg = 0; reg < 4; ++reg) {
      int i = q0 + w * 16 + lg * 4 + reg;
      float rm = -1e30f;
      #pragma unroll
      for (int t = 0; t < 2; ++t) {
        int j = kv0 + t * 16 + li;
        int d = i - j;
        float sv = s[t][reg] * 0.125f;
        sv = (d >= 0) ? (sv + btab[d]) : -1e30f;
        s[t][reg] = sv;
        rm = fmaxf(rm, sv);
      }
      #pragma unroll
      for (int off = 1; off < 16; off <<= 1)
        rm = fmaxf(rm, __shfl_xor(rm, off, 64));
      float mn = fmaxf(mrun[reg], rm);
      float f = __expf(mrun[reg] - mn);     // exp(-inf)=0 on first tile
      mrun[reg] = mn;
      float ps = 0.f;
      #pragma unroll
      for (int t = 0; t < 2; ++t) {
        float p = __expf(s[t][reg] - mn);   // masked -1e30 -> exact 0
        s[t][reg] = p;
        ps += p;
      }
      #pragma unroll
      for (int off = 1; off < 16; off <<= 1)
        ps += __shfl_xor(ps, off, 64);
      lrun[reg] = lrun[reg] * f + ps;
      fac[reg] = f;
    }
    #pragma unroll
    for (int hdt = 0; hdt < 4; ++hdt) {
      O[hdt][0] *= fac[0]; O[hdt][1] *= fac[1];
      O[hdt][2] *= fac[2]; O[hdt][3] *= fac[3];
    }

    // --- P -> LDS (C/D layout -> A-frag layout) ---
    #pragma unroll
    for (int reg = 0; reg < 4; ++reg) {
      Plds[w][lg * 4 + reg][li]      = f2bf(s[0][reg]);
      Plds[w][lg * 4 + reg][16 + li] = f2bf(s[1][reg]);
    }
    __syncthreads();

    // --- O += P V ---
    u16x8 pf = *(const u16x8*)&Plds[w][li][lg * 8];
    #pragma unroll
    for (int hdt = 0; hdt < 4; ++hdt) {
      u16x8 vf = *(const u16x8*)&Vt[hdt * 16 + li][lg * 8];
      O[hdt] = mfma_bf16(pf, vf, O[hdt]);
    }
    __syncthreads();
  }

  // --- epilogue: normalize, IF gain, write [B,N,H*HD] fp32 ---
  const float gain = if_gain[h];
  #pragma unroll
  for (int reg = 0; reg < 4; ++reg) {
    int i = q0 + w * 16 + lg * 4 + reg;
    float scale = gain / lrun[reg];
    float* op = attn_out + ((size_t)b * NSEQ + i) * DMODEL + h * HDIM + li;
    #pragma unroll
    for (int hdt = 0; hdt < 4; ++hdt)
      op[hdt * 16] = O[hdt][reg] * scale;
  }
}

// ---------------------------------------------------------------------------
extern "C" void kernel_launch(void* const* d_in, const int* in_sizes, int n_in,
                              void* d_out, int out_size, void* d_ws,
                              size_t ws_size, hipStream_t stream) {
  const float* x       = (const float*)d_in[0];
  const float* k_delta = (const float*)d_in[1];
  const float* v_delta = (const float*)d_in[2];
  const float* qkv_w   = (const float*)d_in[3];
  const float* qkv_b   = (const float*)d_in[4];
  const float* gate_w  = (const float*)d_in[5];
  const float* gate_b  = (const float*)d_in[6];
  const float* out_w   = (const float*)d_in[7];
  const float* out_b   = (const float*)d_in[8];
  const float* pos_bias = (const float*)d_in[9];
  const float* if_gain  = (const float*)d_in[10];
  float* out = (float*)d_out;
  char* ws = (char*)d_ws;

  // workspace layout (bytes)
  u16*   qbf      = (u16*)(ws + 0);              //  8,388,608
  u16*   kbf      = (u16*)(ws + 8388608);        //  8,388,608
  u16*   vbf      = (u16*)(ws + 16777216);       //  8,388,608
  float* gate_buf = (float*)(ws + 25165824);     // 16,777,216
  float* attn_buf = (float*)(ws + 41943040);     // 16,777,216
  float* bias_tab = (float*)(ws + 58720256);     //     65,536

  bias_tab_kernel<<<dim3(8), dim3(256), 0, stream>>>(pos_bias, bias_tab);

  // qkv GEMM + pack q/k/v (k_delta/v_delta fused)
  gemm_kernel<1536, 0, 0><<<dim3(24, 128), dim3(256), 0, stream>>>(
      x, nullptr, qkv_w, qkv_b, k_delta, v_delta, qbf, kbf, vbf, nullptr);

  // gate GEMM -> sigmoid fp32
  gemm_kernel<512, 0, 1><<<dim3(8, 128), dim3(256), 0, stream>>>(
      x, nullptr, gate_w, gate_b, nullptr, nullptr, nullptr, nullptr, nullptr,
      gate_buf);

  // flash attention
  attn_kernel<<<dim3(1024), dim3(256), 0, stream>>>(qbf, kbf, vbf, bias_tab,
                                                    if_gain, attn_buf);

  // final gated GEMM -> d_out
  gemm_kernel<512, 1, 2><<<dim3(8, 128), dim3(256), 0, stream>>>(
      attn_buf, gate_buf, out_w, out_b, nullptr, nullptr, nullptr, nullptr,
      nullptr, out);

  (void)in_sizes; (void)n_in; (void)out_size; (void)ws_size;
}

// Round 3
// 236.808 us; speedup vs baseline: 1.7279x; 1.7279x over previous
//
#include <hip/hip_runtime.h>
#include <cmath>

typedef unsigned short u16;
typedef unsigned short u16x4 __attribute__((ext_vector_type(4)));
typedef unsigned short u16x8 __attribute__((ext_vector_type(8)));
typedef __bf16 bf16x8 __attribute__((ext_vector_type(8)));
typedef float f32x4 __attribute__((ext_vector_type(4)));

#define HNUM 8
#define HDIM 64
#define BATCH 4
#define NSEQ 2048
#define DMODEL 512
#define LP 72   // padded LDS row stride in u16 (144 B, 16B-aligned rows)

__device__ __forceinline__ u16 f2bf(float f) {
  unsigned int u = __builtin_bit_cast(unsigned int, f);
  u += 0x7fffu + ((u >> 16) & 1u);          // round-to-nearest-even
  return (u16)(u >> 16);
}

__device__ __forceinline__ f32x4 mfma_bf16(u16x8 a, u16x8 b, f32x4 c) {
  return __builtin_amdgcn_mfma_f32_16x16x32_bf16(
      __builtin_bit_cast(bf16x8, a), __builtin_bit_cast(bf16x8, b), c, 0, 0, 0);
}

// ---------------------------------------------------------------------------
// Bias table: tab[h][d] = in_band(bucket(d),h) ? pos_bias[bucket(d)][h] : -100
// ---------------------------------------------------------------------------
__global__ __launch_bounds__(256) void bias_tab_kernel(
    const float* __restrict__ pos_bias, float* __restrict__ tab) {
  int d = blockIdx.x * 256 + threadIdx.x;   // 0..2047
  if (d >= NSEQ) return;
  int bkt;
  if (d < 28) {
    bkt = d;
  } else {
    double t = log((double)d / 28.0) / log(2048.0 / 28.0) * 16.0;
    int ti = 28 + (int)t;                   // truncation == astype(int32), t>=0
    bkt = ti < 43 ? ti : 43;
  }
  const int lo[8] = {38, 34, 28, 20, 13, 7, 3, 0};
  const int hi[8] = {44, 40, 35, 28, 21, 14, 9, 6};
  #pragma unroll
  for (int h = 0; h < HNUM; ++h) {
    bool inb = (bkt >= lo[h]) && (bkt < hi[h]);
    tab[h * NSEQ + d] = inb ? pos_bias[bkt * HNUM + h] : -100.0f;
  }
}

// ---------------------------------------------------------------------------
// Generic bf16-MFMA GEMM: C[M,NCOLS] = A[M,512] @ W[512,NCOLS] + bias
// ---------------------------------------------------------------------------
template <int NCOLS, int STAGE, int EPI>
__global__ __launch_bounds__(256) void gemm_kernel(
    const float* __restrict__ A, const float* __restrict__ A2,
    const float* __restrict__ W, const float* __restrict__ bias,
    const float* __restrict__ kdelta, const float* __restrict__ vdelta,
    u16* __restrict__ qbf, u16* __restrict__ kbf, u16* __restrict__ vbf,
    float* __restrict__ outp) {
  __shared__ u16 As[64][32];   // [m][k] bf16
  __shared__ u16 Ws[64][32];   // [n][k] bf16 (transposed)

  const int m0 = blockIdx.y * 64;
  const int n0 = blockIdx.x * 64;
  const int tid = threadIdx.x;
  const int w = tid >> 6, l = tid & 63, li = l & 15, lg = l >> 4;

  f32x4 acc[4] = {{0.f,0.f,0.f,0.f},{0.f,0.f,0.f,0.f},
                  {0.f,0.f,0.f,0.f},{0.f,0.f,0.f,0.f}};

  const int ar = tid >> 2;
  const int ac = (tid & 3) << 3;
  const int wk = tid >> 3;
  const int wn = (tid & 7) << 3;

  for (int kt = 0; kt < DMODEL / 32; ++kt) {
    const float* ap = A + (size_t)(m0 + ar) * DMODEL + kt * 32 + ac;
    float4 f0 = *(const float4*)ap;
    float4 f1 = *(const float4*)(ap + 4);
    if constexpr (STAGE == 1) {
      const float* gp = A2 + (size_t)(m0 + ar) * DMODEL + kt * 32 + ac;
      float4 g0 = *(const float4*)gp;
      float4 g1 = *(const float4*)(gp + 4);
      f0.x *= g0.x; f0.y *= g0.y; f0.z *= g0.z; f0.w *= g0.w;
      f1.x *= g1.x; f1.y *= g1.y; f1.z *= g1.z; f1.w *= g1.w;
    }
    u16x8 pk;
    pk[0] = f2bf(f0.x); pk[1] = f2bf(f0.y); pk[2] = f2bf(f0.z); pk[3] = f2bf(f0.w);
    pk[4] = f2bf(f1.x); pk[5] = f2bf(f1.y); pk[6] = f2bf(f1.z); pk[7] = f2bf(f1.w);
    *(u16x8*)&As[ar][ac] = pk;

    const float* wp = W + (size_t)(kt * 32 + wk) * NCOLS + n0 + wn;
    float4 w0 = *(const float4*)wp;
    float4 w1 = *(const float4*)(wp + 4);
    Ws[wn + 0][wk] = f2bf(w0.x); Ws[wn + 1][wk] = f2bf(w0.y);
    Ws[wn + 2][wk] = f2bf(w0.z); Ws[wn + 3][wk] = f2bf(w0.w);
    Ws[wn + 4][wk] = f2bf(w1.x); Ws[wn + 5][wk] = f2bf(w1.y);
    Ws[wn + 6][wk] = f2bf(w1.z); Ws[wn + 7][wk] = f2bf(w1.w);
    __syncthreads();

    u16x8 af = *(const u16x8*)&As[w * 16 + li][lg * 8];
    #pragma unroll
    for (int ct = 0; ct < 4; ++ct) {
      u16x8 bfv = *(const u16x8*)&Ws[ct * 16 + li][lg * 8];
      acc[ct] = mfma_bf16(af, bfv, acc[ct]);
    }
    __syncthreads();
  }

  #pragma unroll
  for (int ct = 0; ct < 4; ++ct) {
    int colg = n0 + ct * 16 + li;
    #pragma unroll
    for (int reg = 0; reg < 4; ++reg) {
      int rowg = m0 + w * 16 + lg * 4 + reg;
      float val = acc[ct][reg] + bias[colg];
      if constexpr (EPI == 0) {
        int which = colg >> 9;           // 0=q 1=k 2=v
        int inner = colg & 511;
        int hh = inner >> 6, hd = inner & 63;
        int bb = rowg >> 11, nn = rowg & 2047;
        size_t idx = (((size_t)bb * HNUM + hh) * NSEQ + nn) * HDIM + hd;
        if (which == 0)      qbf[idx] = f2bf(val * 0.125f);  // fold 1/sqrt(HD)
        else if (which == 1) kbf[idx] = f2bf(val + kdelta[idx]);
        else                 vbf[idx] = f2bf(val + vdelta[idx]);
      } else if constexpr (EPI == 1) {
        outp[(size_t)rowg * NCOLS + colg] = 1.f / (1.f + __expf(-val));
      } else {
        outp[(size_t)rowg * NCOLS + colg] = val;
      }
    }
  }
}

// ---------------------------------------------------------------------------
// Flash attention, swapped-QK^T layout, per-head banded KV-range skipping.
// Block = 64 q-rows (4 waves x 16), KV tiles of 64.
// Swapped mfma(K,Q): lane (li,lg) holds S^T[j=kv0+16t+4lg+r][i=q0+16w+li]
// -> softmax row stats are per-lane over 16 regs + 2 shuffles.
// LDS: padded stride 72 u16 (no swizzle this round — bisect build).
// ---------------------------------------------------------------------------
__global__ __launch_bounds__(256) void attn_kernel(
    const u16* __restrict__ qbf, const u16* __restrict__ kbf,
    const u16* __restrict__ vbf, const float* __restrict__ bias_tab,
    const float* __restrict__ if_gain, float* __restrict__ attn_out) {
  __shared__ u16 Ks[64][LP];      // [kv][hd]
  __shared__ u16 Vt[64][LP];      // [hd][kv]
  __shared__ u16 Pl[4][16][LP];   // per-wave [i][j]

  // Per-head in-band distance windows (+-2 margin; bias table is the exact
  // arbiter — margins only add -100 columns).
  static const int DMINW[8] = {408, 139, 26, 18, 11, 5, 1, 0};
  static const int DMAXW[8] = {2049, 702, 185, 29, 22, 15, 10, 7};
  static const int DMINS[8] = {412, 143, 30, 22, 15, 9, 5, 2};

  const int h = blockIdx.x >> 7;          // heavy heads first
  const int rem = blockIdx.x & 127;
  const int qt = 31 - (rem >> 2);         // long q-tiles first
  const int b = rem & 3;
  const int bh = b * HNUM + h;
  const int q0 = qt * 64;
  const int tid = threadIdx.x;
  const int w = tid >> 6, l = tid & 63, li = l & 15, lg = l >> 4;

  const u16* qrow = qbf + ((size_t)bh * NSEQ + q0 + w * 16 + li) * HDIM;
  u16x8 qf0 = *(const u16x8*)(qrow + lg * 8);
  u16x8 qf1 = *(const u16x8*)(qrow + 32 + lg * 8);

  const bool pure = q0 >= DMINS[h];   // all rows have an in-band column
  int kv_lo = 0, kv_hi = q0 + 64;
  if (pure) {
    int lo = q0 - DMAXW[h];
    kv_lo = (lo > 0 ? lo : 0) & ~63;
    kv_hi = q0 + 64 - DMINW[h];
  }
  const int t0 = kv_lo >> 6, t1 = (kv_hi - 1) >> 6;

  const int srow = tid >> 2;          // 0..63 staging row
  const int scb = (tid & 3) << 4;     // 0,16,32,48 staging col block
  const float* btab = bias_tab + h * NSEQ;

  float mrun = -INFINITY, lrun = 0.f;
  f32x4 O[4] = {{0.f,0.f,0.f,0.f},{0.f,0.f,0.f,0.f},
                {0.f,0.f,0.f,0.f},{0.f,0.f,0.f,0.f}};

  for (int tt = t0; tt <= t1; ++tt) {
    const int kv0 = tt << 6;
    // ---- stage K tile and transposed V tile ----
    {
      const size_t gbase = ((size_t)bh * NSEQ + kv0 + srow) * HDIM + scb;
      u16x8 k0 = *(const u16x8*)(kbf + gbase);
      u16x8 k1 = *(const u16x8*)(kbf + gbase + 8);
      u16x8 v0 = *(const u16x8*)(vbf + gbase);
      u16x8 v1 = *(const u16x8*)(vbf + gbase + 8);
      *(u16x8*)&Ks[srow][scb] = k0;
      *(u16x8*)&Ks[srow][scb + 8] = k1;
      #pragma unroll
      for (int jj = 0; jj < 8; ++jj) {
        Vt[scb + jj][srow] = v0[jj];
        Vt[scb + 8 + jj][srow] = v1[jj];
      }
    }
    __syncthreads();

    // ---- S^T = K Q^T : 4 j-tiles x (K=64 -> 2 mfma) ----
    f32x4 s[4];
    #pragma unroll
    for (int t = 0; t < 4; ++t) {
      u16x8 a0 = *(const u16x8*)&Ks[t * 16 + li][lg * 8];
      u16x8 a1 = *(const u16x8*)&Ks[t * 16 + li][32 + lg * 8];
      f32x4 acc = {0.f, 0.f, 0.f, 0.f};
      acc = mfma_bf16(a0, qf0, acc);
      acc = mfma_bf16(a1, qf1, acc);
      s[t] = acc;
    }

    // ---- bias + causal mask + online softmax (lane owns row i) ----
    const int D0 = (q0 + w * 16 + li) - kv0 - lg * 4;  // d = D0 - 16t - r
    float rm = -1e30f;
    #pragma unroll
    for (int t = 0; t < 4; ++t) {
      #pragma unroll
      for (int r = 0; r < 4; ++r) {
        int d = D0 - 16 * t - r;
        float sv = s[t][r];
        sv = (d >= 0) ? (sv + btab[d]) : -1e30f;
        s[t][r] = sv;
        rm = fmaxf(rm, sv);
      }
    }
    rm = fmaxf(rm, __shfl_xor(rm, 16, 64));
    rm = fmaxf(rm, __shfl_xor(rm, 32, 64));
    const float mn = fmaxf(mrun, rm);
    const float f = __expf(mrun - mn);   // exp(-inf)=0 on first tile
    mrun = mn;
    float ps = 0.f;
    #pragma unroll
    for (int t = 0; t < 4; ++t) {
      #pragma unroll
      for (int r = 0; r < 4; ++r) {
        float p = __expf(s[t][r] - mn);
        s[t][r] = p;
        ps += p;
      }
    }
    ps += __shfl_xor(ps, 16, 64);
    ps += __shfl_xor(ps, 32, 64);
    lrun = lrun * f + ps;

    // ---- P -> per-wave LDS (transpose to A-frag layout) ----
    #pragma unroll
    for (int t = 0; t < 4; ++t) {
      u16x4 pk;
      pk[0] = f2bf(s[t][0]); pk[1] = f2bf(s[t][1]);
      pk[2] = f2bf(s[t][2]); pk[3] = f2bf(s[t][3]);
      *(u16x4*)&Pl[w][li][t * 16 + lg * 4] = pk;
    }

    // ---- O rescale (broadcast f from lane holding row lg*4+r) ----
    float fr[4];
    #pragma unroll
    for (int r = 0; r < 4; ++r) fr[r] = __shfl(f, lg * 4 + r, 64);
    #pragma unroll
    for (int dt = 0; dt < 4; ++dt) {
      O[dt][0] *= fr[0]; O[dt][1] *= fr[1];
      O[dt][2] *= fr[2]; O[dt][3] *= fr[3];
    }
    __syncthreads();

    // ---- O += P V ----
    #pragma unroll
    for (int ks = 0; ks < 2; ++ks) {
      u16x8 pA = *(const u16x8*)&Pl[w][li][ks * 32 + lg * 8];
      #pragma unroll
      for (int dt = 0; dt < 4; ++dt) {
        u16x8 vB = *(const u16x8*)&Vt[dt * 16 + li][ks * 32 + lg * 8];
        O[dt] = mfma_bf16(pA, vB, O[dt]);
      }
    }
    __syncthreads();
  }

  // ---- epilogue: normalize, IF gain, write [B,N,H*HD] fp32 ----
  const float gain = if_gain[h];
  float linv[4];
  #pragma unroll
  for (int r = 0; r < 4; ++r)
    linv[r] = gain / __shfl(lrun, lg * 4 + r, 64);
  #pragma unroll
  for (int r = 0; r < 4; ++r) {
    const int i = q0 + w * 16 + lg * 4 + r;
    float* op = attn_out + ((size_t)b * NSEQ + i) * DMODEL + h * HDIM + li;
    #pragma unroll
    for (int dt = 0; dt < 4; ++dt)
      op[dt * 16] = O[dt][r] * linv[r];
  }
}

// ---------------------------------------------------------------------------
extern "C" void kernel_launch(void* const* d_in, const int* in_sizes, int n_in,
                              void* d_out, int out_size, void* d_ws,
                              size_t ws_size, hipStream_t stream) {
  const float* x       = (const float*)d_in[0];
  const float* k_delta = (const float*)d_in[1];
  const float* v_delta = (const float*)d_in[2];
  const float* qkv_w   = (const float*)d_in[3];
  const float* qkv_b   = (const float*)d_in[4];
  const float* gate_w  = (const float*)d_in[5];
  const float* gate_b  = (const float*)d_in[6];
  const float* out_w   = (const float*)d_in[7];
  const float* out_b   = (const float*)d_in[8];
  const float* pos_bias = (const float*)d_in[9];
  const float* if_gain  = (const float*)d_in[10];
  float* out = (float*)d_out;
  char* ws = (char*)d_ws;

  u16*   qbf      = (u16*)(ws + 0);              //  8,388,608
  u16*   kbf      = (u16*)(ws + 8388608);        //  8,388,608
  u16*   vbf      = (u16*)(ws + 16777216);       //  8,388,608
  float* gate_buf = (float*)(ws + 25165824);     // 16,777,216
  float* attn_buf = (float*)(ws + 41943040);     // 16,777,216
  float* bias_tab = (float*)(ws + 58720256);     //     65,536

  bias_tab_kernel<<<dim3(8), dim3(256), 0, stream>>>(pos_bias, bias_tab);

  gemm_kernel<1536, 0, 0><<<dim3(24, 128), dim3(256), 0, stream>>>(
      x, nullptr, qkv_w, qkv_b, k_delta, v_delta, qbf, kbf, vbf, nullptr);

  gemm_kernel<512, 0, 1><<<dim3(8, 128), dim3(256), 0, stream>>>(
      x, nullptr, gate_w, gate_b, nullptr, nullptr, nullptr, nullptr, nullptr,
      gate_buf);

  attn_kernel<<<dim3(1024), dim3(256), 0, stream>>>(qbf, kbf, vbf, bias_tab,
                                                    if_gain, attn_buf);

  gemm_kernel<512, 1, 2><<<dim3(8, 128), dim3(256), 0, stream>>>(
      attn_buf, gate_buf, out_w, out_b, nullptr, nullptr, nullptr, nullptr,
      nullptr, out);

  (void)in_sizes; (void)n_in; (void)out_size; (void)ws_size;
}

// Round 4
// 162.864 us; speedup vs baseline: 2.5124x; 1.4540x over previous
//
#include <hip/hip_runtime.h>
#include <cmath>

typedef unsigned short u16;
typedef unsigned short u16x4 __attribute__((ext_vector_type(4)));
typedef unsigned short u16x8 __attribute__((ext_vector_type(8)));
typedef __bf16 bf16x8 __attribute__((ext_vector_type(8)));
typedef float f32x4 __attribute__((ext_vector_type(4)));

#define HNUM 8
#define HDIM 64
#define BATCH 4
#define NSEQ 2048
#define DMODEL 512
#define LP 72   // padded LDS row stride in u16 (144 B) for the attn kernel

__device__ __forceinline__ u16 f2bf(float f) {
  unsigned int u = __builtin_bit_cast(unsigned int, f);
  u += 0x7fffu + ((u >> 16) & 1u);          // round-to-nearest-even
  return (u16)(u >> 16);
}

__device__ __forceinline__ float bf2f(u16 v) {
  unsigned int u = ((unsigned int)v) << 16;
  return __builtin_bit_cast(float, u);
}

__device__ __forceinline__ f32x4 mfma_bf16(u16x8 a, u16x8 b, f32x4 c) {
  return __builtin_amdgcn_mfma_f32_16x16x32_bf16(
      __builtin_bit_cast(bf16x8, a), __builtin_bit_cast(bf16x8, b), c, 0, 0, 0);
}

// async global->LDS, 16 B per lane (dest must be wave-uniform base + lane*16)
__device__ __forceinline__ void gload16(u16* lds, const u16* g) {
  __builtin_amdgcn_global_load_lds(
      (const __attribute__((address_space(1))) void*)g,
      (__attribute__((address_space(3))) void*)lds, 16, 0, 0);
}

// ---------------------------------------------------------------------------
// Prep: fp32 -> bf16 convert (x), 8 elems/thread
// ---------------------------------------------------------------------------
__global__ __launch_bounds__(256) void cvt_bf16_kernel(
    const float* __restrict__ in, u16* __restrict__ out, int n8) {
  int i = blockIdx.x * 256 + threadIdx.x;
  if (i >= n8) return;
  const float4 f0 = *(const float4*)(in + i * 8);
  const float4 f1 = *(const float4*)(in + i * 8 + 4);
  u16x8 pk;
  pk[0] = f2bf(f0.x); pk[1] = f2bf(f0.y); pk[2] = f2bf(f0.z); pk[3] = f2bf(f0.w);
  pk[4] = f2bf(f1.x); pk[5] = f2bf(f1.y); pk[6] = f2bf(f1.z); pk[7] = f2bf(f1.w);
  *(u16x8*)(out + i * 8) = pk;
}

// ---------------------------------------------------------------------------
// Prep: W[K][N] fp32 -> Wt[N][K] bf16 (32x32 LDS tile transpose)
// ---------------------------------------------------------------------------
__global__ __launch_bounds__(256) void transpose_w_kernel(
    const float* __restrict__ W, u16* __restrict__ Wt, int K, int N) {
  __shared__ float tile[32][33];
  const int n0 = blockIdx.x * 32, k0 = blockIdx.y * 32;
  const int tx = threadIdx.x & 31, ty = threadIdx.x >> 5;
  #pragma unroll
  for (int yy = ty; yy < 32; yy += 8)
    tile[yy][tx] = W[(size_t)(k0 + yy) * N + n0 + tx];
  __syncthreads();
  #pragma unroll
  for (int yy = ty; yy < 32; yy += 8)
    Wt[(size_t)(n0 + yy) * K + k0 + tx] = f2bf(tile[tx][yy]);
}

// ---------------------------------------------------------------------------
// Bias table: tab[h][d] = in_band(bucket(d),h) ? pos_bias[bucket(d)][h] : -100
// ---------------------------------------------------------------------------
__global__ __launch_bounds__(256) void bias_tab_kernel(
    const float* __restrict__ pos_bias, float* __restrict__ tab) {
  int d = blockIdx.x * 256 + threadIdx.x;   // 0..2047
  if (d >= NSEQ) return;
  int bkt;
  if (d < 28) {
    bkt = d;
  } else {
    double t = log((double)d / 28.0) / log(2048.0 / 28.0) * 16.0;
    int ti = 28 + (int)t;
    bkt = ti < 43 ? ti : 43;
  }
  const int lo[8] = {38, 34, 28, 20, 13, 7, 3, 0};
  const int hi[8] = {44, 40, 35, 28, 21, 14, 9, 6};
  #pragma unroll
  for (int h = 0; h < HNUM; ++h) {
    bool inb = (bkt >= lo[h]) && (bkt < hi[h]);
    tab[h * NSEQ + d] = inb ? pos_bias[bkt * HNUM + h] : -100.0f;
  }
}

// ---------------------------------------------------------------------------
// m97-style bf16 GEMM: C[M,NCOLS] = Abf[M,512] @ Wt[NCOLS,512]^T + bias
// 128x128 tile, BK=32, 4 waves (2x2, each 64x64 = 4x4 frags), global_load_lds.
// EPI 0: pack q/k/v (+deltas, q*0.125) | 1: sigmoid -> bf16 | 2: fp32 out
// ---------------------------------------------------------------------------
template <int NCOLS, int EPI>
__global__ __launch_bounds__(256) void gemm_bf16(
    const u16* __restrict__ Abf, const u16* __restrict__ Wt,
    const float* __restrict__ bias,
    const float* __restrict__ kdelta, const float* __restrict__ vdelta,
    u16* __restrict__ qbf, u16* __restrict__ kbf, u16* __restrict__ vbf,
    u16* __restrict__ outbf, float* __restrict__ outf) {
  __shared__ __align__(16) u16 As[128 * 32];
  __shared__ __align__(16) u16 Bs[128 * 32];

  const int m0 = blockIdx.y * 128;
  const int n0 = blockIdx.x * 128;
  const int tid = threadIdx.x;
  const int w = tid >> 6, l = tid & 63, li = l & 15, lg = l >> 4;
  const int wr = w >> 1, wc = w & 1;

  f32x4 acc[4][4];
  #pragma unroll
  for (int i = 0; i < 4; ++i)
    #pragma unroll
    for (int j = 0; j < 4; ++j) acc[i][j] = f32x4{0.f, 0.f, 0.f, 0.f};

  for (int kt = 0; kt < DMODEL / 32; ++kt) {
    #pragma unroll
    for (int i = 0; i < 2; ++i) {
      const int off = (i * 256 + tid) * 8;        // u16 units; dst linear
      const int row = off >> 5, col = off & 31;
      gload16(&As[off], Abf + (size_t)(m0 + row) * DMODEL + kt * 32 + col);
      gload16(&Bs[off], Wt + (size_t)(n0 + row) * DMODEL + kt * 32 + col);
    }
    __syncthreads();   // drains vmcnt -> LDS ready

    u16x8 af[4], bfr[4];
    #pragma unroll
    for (int mt = 0; mt < 4; ++mt)
      af[mt] = *(const u16x8*)&As[(wr * 64 + mt * 16 + li) * 32 + lg * 8];
    #pragma unroll
    for (int nt = 0; nt < 4; ++nt)
      bfr[nt] = *(const u16x8*)&Bs[(wc * 64 + nt * 16 + li) * 32 + lg * 8];
    #pragma unroll
    for (int mt = 0; mt < 4; ++mt)
      #pragma unroll
      for (int nt = 0; nt < 4; ++nt)
        acc[mt][nt] = mfma_bf16(af[mt], bfr[nt], acc[mt][nt]);
    __syncthreads();
  }

  // epilogue: row = m0+wr*64+mt*16+lg*4+r ; col = n0+wc*64+nt*16+li
  #pragma unroll
  for (int nt = 0; nt < 4; ++nt) {
    const int colg = n0 + wc * 64 + nt * 16 + li;
    const float bv = bias[colg];
    #pragma unroll
    for (int mt = 0; mt < 4; ++mt) {
      #pragma unroll
      for (int r = 0; r < 4; ++r) {
        const int rowg = m0 + wr * 64 + mt * 16 + lg * 4 + r;
        float val = acc[mt][nt][r] + bv;
        if constexpr (EPI == 0) {
          const int which = colg >> 9;          // 0=q 1=k 2=v (uniform/block)
          const int inner = colg & 511;
          const int hh = inner >> 6, hd = inner & 63;
          const int bb = rowg >> 11, nn = rowg & 2047;
          const size_t idx = (((size_t)bb * HNUM + hh) * NSEQ + nn) * HDIM + hd;
          if (which == 0)      qbf[idx] = f2bf(val * 0.125f);
          else if (which == 1) kbf[idx] = f2bf(val + kdelta[idx]);
          else                 vbf[idx] = f2bf(val + vdelta[idx]);
        } else if constexpr (EPI == 1) {
          outbf[(size_t)rowg * NCOLS + colg] = f2bf(1.f / (1.f + __expf(-val)));
        } else {
          outf[(size_t)rowg * NCOLS + colg] = val;
        }
      }
    }
  }
}

// ---------------------------------------------------------------------------
// Flash attention (round-3-verified body), swapped-QK^T, banded KV skipping.
// Epilogue now: multiply by sigmoid gate (bf16) and write bf16.
// ---------------------------------------------------------------------------
__global__ __launch_bounds__(256) void attn_kernel(
    const u16* __restrict__ qbf, const u16* __restrict__ kbf,
    const u16* __restrict__ vbf, const float* __restrict__ bias_tab,
    const float* __restrict__ if_gain, const u16* __restrict__ gate,
    u16* __restrict__ attn_out) {
  __shared__ __align__(16) u16 Ks[64][LP];
  __shared__ __align__(16) u16 Vt[64][LP];
  __shared__ __align__(16) u16 Pl[4][16][LP];

  static const int DMINW[8] = {408, 139, 26, 18, 11, 5, 1, 0};
  static const int DMAXW[8] = {2049, 702, 185, 29, 22, 15, 10, 7};
  static const int DMINS[8] = {412, 143, 30, 22, 15, 9, 5, 2};

  const int h = blockIdx.x >> 7;
  const int rem = blockIdx.x & 127;
  const int qt = 31 - (rem >> 2);
  const int b = rem & 3;
  const int bh = b * HNUM + h;
  const int q0 = qt * 64;
  const int tid = threadIdx.x;
  const int w = tid >> 6, l = tid & 63, li = l & 15, lg = l >> 4;

  const u16* qrow = qbf + ((size_t)bh * NSEQ + q0 + w * 16 + li) * HDIM;
  u16x8 qf0 = *(const u16x8*)(qrow + lg * 8);
  u16x8 qf1 = *(const u16x8*)(qrow + 32 + lg * 8);

  const bool pure = q0 >= DMINS[h];
  int kv_lo = 0, kv_hi = q0 + 64;
  if (pure) {
    int lo = q0 - DMAXW[h];
    kv_lo = (lo > 0 ? lo : 0) & ~63;
    kv_hi = q0 + 64 - DMINW[h];
  }
  const int t0 = kv_lo >> 6, t1 = (kv_hi - 1) >> 6;

  const int srow = tid >> 2;
  const int scb = (tid & 3) << 4;
  const float* btab = bias_tab + h * NSEQ;

  float mrun = -INFINITY, lrun = 0.f;
  f32x4 O[4] = {{0.f,0.f,0.f,0.f},{0.f,0.f,0.f,0.f},
                {0.f,0.f,0.f,0.f},{0.f,0.f,0.f,0.f}};

  for (int tt = t0; tt <= t1; ++tt) {
    const int kv0 = tt << 6;
    {
      const size_t gbase = ((size_t)bh * NSEQ + kv0 + srow) * HDIM + scb;
      u16x8 k0 = *(const u16x8*)(kbf + gbase);
      u16x8 k1 = *(const u16x8*)(kbf + gbase + 8);
      u16x8 v0 = *(const u16x8*)(vbf + gbase);
      u16x8 v1 = *(const u16x8*)(vbf + gbase + 8);
      *(u16x8*)&Ks[srow][scb] = k0;
      *(u16x8*)&Ks[srow][scb + 8] = k1;
      #pragma unroll
      for (int jj = 0; jj < 8; ++jj) {
        Vt[scb + jj][srow] = v0[jj];
        Vt[scb + 8 + jj][srow] = v1[jj];
      }
    }
    __syncthreads();

    f32x4 s[4];
    #pragma unroll
    for (int t = 0; t < 4; ++t) {
      u16x8 a0 = *(const u16x8*)&Ks[t * 16 + li][lg * 8];
      u16x8 a1 = *(const u16x8*)&Ks[t * 16 + li][32 + lg * 8];
      f32x4 acc = {0.f, 0.f, 0.f, 0.f};
      acc = mfma_bf16(a0, qf0, acc);
      acc = mfma_bf16(a1, qf1, acc);
      s[t] = acc;
    }

    const int D0 = (q0 + w * 16 + li) - kv0 - lg * 4;
    float rm = -1e30f;
    #pragma unroll
    for (int t = 0; t < 4; ++t) {
      #pragma unroll
      for (int r = 0; r < 4; ++r) {
        int d = D0 - 16 * t - r;
        float sv = s[t][r];
        sv = (d >= 0) ? (sv + btab[d]) : -1e30f;
        s[t][r] = sv;
        rm = fmaxf(rm, sv);
      }
    }
    rm = fmaxf(rm, __shfl_xor(rm, 16, 64));
    rm = fmaxf(rm, __shfl_xor(rm, 32, 64));
    const float mn = fmaxf(mrun, rm);
    const float f = __expf(mrun - mn);
    mrun = mn;
    float ps = 0.f;
    #pragma unroll
    for (int t = 0; t < 4; ++t) {
      #pragma unroll
      for (int r = 0; r < 4; ++r) {
        float p = __expf(s[t][r] - mn);
        s[t][r] = p;
        ps += p;
      }
    }
    ps += __shfl_xor(ps, 16, 64);
    ps += __shfl_xor(ps, 32, 64);
    lrun = lrun * f + ps;

    #pragma unroll
    for (int t = 0; t < 4; ++t) {
      u16x4 pk;
      pk[0] = f2bf(s[t][0]); pk[1] = f2bf(s[t][1]);
      pk[2] = f2bf(s[t][2]); pk[3] = f2bf(s[t][3]);
      *(u16x4*)&Pl[w][li][t * 16 + lg * 4] = pk;
    }

    float fr[4];
    #pragma unroll
    for (int r = 0; r < 4; ++r) fr[r] = __shfl(f, lg * 4 + r, 64);
    #pragma unroll
    for (int dt = 0; dt < 4; ++dt) {
      O[dt][0] *= fr[0]; O[dt][1] *= fr[1];
      O[dt][2] *= fr[2]; O[dt][3] *= fr[3];
    }
    __syncthreads();

    #pragma unroll
    for (int ks = 0; ks < 2; ++ks) {
      u16x8 pA = *(const u16x8*)&Pl[w][li][ks * 32 + lg * 8];
      #pragma unroll
      for (int dt = 0; dt < 4; ++dt) {
        u16x8 vB = *(const u16x8*)&Vt[dt * 16 + li][ks * 32 + lg * 8];
        O[dt] = mfma_bf16(pA, vB, O[dt]);
      }
    }
    __syncthreads();
  }

  // epilogue: normalize, IF gain, multiply gate, write bf16 [B,N,D]
  const float gain = if_gain[h];
  float linv[4];
  #pragma unroll
  for (int r = 0; r < 4; ++r)
    linv[r] = gain / __shfl(lrun, lg * 4 + r, 64);
  #pragma unroll
  for (int r = 0; r < 4; ++r) {
    const int i = q0 + w * 16 + lg * 4 + r;
    const size_t base = ((size_t)b * NSEQ + i) * DMODEL + h * HDIM + li;
    #pragma unroll
    for (int dt = 0; dt < 4; ++dt) {
      const float g = bf2f(gate[base + dt * 16]);
      attn_out[base + dt * 16] = f2bf(O[dt][r] * linv[r] * g);
    }
  }
}

// ---------------------------------------------------------------------------
extern "C" void kernel_launch(void* const* d_in, const int* in_sizes, int n_in,
                              void* d_out, int out_size, void* d_ws,
                              size_t ws_size, hipStream_t stream) {
  const float* x       = (const float*)d_in[0];
  const float* k_delta = (const float*)d_in[1];
  const float* v_delta = (const float*)d_in[2];
  const float* qkv_w   = (const float*)d_in[3];
  const float* qkv_b   = (const float*)d_in[4];
  const float* gate_w  = (const float*)d_in[5];
  const float* gate_b  = (const float*)d_in[6];
  const float* out_w   = (const float*)d_in[7];
  const float* out_b   = (const float*)d_in[8];
  const float* pos_bias = (const float*)d_in[9];
  const float* if_gain  = (const float*)d_in[10];
  float* out = (float*)d_out;
  char* ws = (char*)d_ws;

  // workspace layout (bytes)
  u16*   xbf      = (u16*)(ws + 0);              //  8,388,608
  u16*   qbf      = (u16*)(ws + 8388608);        //  8,388,608
  u16*   kbf      = (u16*)(ws + 16777216);       //  8,388,608
  u16*   vbf      = (u16*)(ws + 25165824);       //  8,388,608
  u16*   gate_buf = (u16*)(ws + 33554432);       //  8,388,608
  u16*   attn_buf = (u16*)(ws + 41943040);       //  8,388,608
  u16*   qkv_wt   = (u16*)(ws + 50331648);       //  1,572,864
  u16*   gate_wt  = (u16*)(ws + 51904512);       //    524,288
  u16*   out_wt   = (u16*)(ws + 52428800);       //    524,288
  float* bias_tab = (float*)(ws + 52953088);     //     65,536

  // prep
  cvt_bf16_kernel<<<dim3(2048), dim3(256), 0, stream>>>(
      x, xbf, BATCH * NSEQ * DMODEL / 8);
  transpose_w_kernel<<<dim3(48, 16), dim3(256), 0, stream>>>(
      qkv_w, qkv_wt, DMODEL, 3 * DMODEL);
  transpose_w_kernel<<<dim3(16, 16), dim3(256), 0, stream>>>(
      gate_w, gate_wt, DMODEL, DMODEL);
  transpose_w_kernel<<<dim3(16, 16), dim3(256), 0, stream>>>(
      out_w, out_wt, DMODEL, DMODEL);
  bias_tab_kernel<<<dim3(8), dim3(256), 0, stream>>>(pos_bias, bias_tab);

  // qkv GEMM + pack
  gemm_bf16<1536, 0><<<dim3(12, 64), dim3(256), 0, stream>>>(
      xbf, qkv_wt, qkv_b, k_delta, v_delta, qbf, kbf, vbf, nullptr, nullptr);

  // gate GEMM -> sigmoid bf16
  gemm_bf16<512, 1><<<dim3(4, 64), dim3(256), 0, stream>>>(
      xbf, gate_wt, gate_b, nullptr, nullptr, nullptr, nullptr, nullptr,
      gate_buf, nullptr);

  // flash attention (gate fused in epilogue)
  attn_kernel<<<dim3(1024), dim3(256), 0, stream>>>(
      qbf, kbf, vbf, bias_tab, if_gain, gate_buf, attn_buf);

  // final GEMM -> d_out (fp32)
  gemm_bf16<512, 2><<<dim3(4, 64), dim3(256), 0, stream>>>(
      attn_buf, out_wt, out_b, nullptr, nullptr, nullptr, nullptr, nullptr,
      nullptr, out);

  (void)in_sizes; (void)n_in; (void)out_size; (void)ws_size;
}

// Round 5
// 130.521 us; speedup vs baseline: 3.1349x; 1.2478x over previous
//
#include <hip/hip_runtime.h>
#include <cmath>

typedef unsigned short u16;
typedef unsigned short u16x4 __attribute__((ext_vector_type(4)));
typedef unsigned short u16x8 __attribute__((ext_vector_type(8)));
typedef __bf16 bf16x8 __attribute__((ext_vector_type(8)));
typedef float f32x4 __attribute__((ext_vector_type(4)));

#define HNUM 8
#define HDIM 64
#define BATCH 4
#define NSEQ 2048
#define DMODEL 512
#define LP 72   // padded LDS row stride in u16 (144 B) for the attn kernel

__device__ __forceinline__ u16 f2bf(float f) {
  unsigned int u = __builtin_bit_cast(unsigned int, f);
  u += 0x7fffu + ((u >> 16) & 1u);          // round-to-nearest-even
  return (u16)(u >> 16);
}

__device__ __forceinline__ float bf2f(u16 v) {
  unsigned int u = ((unsigned int)v) << 16;
  return __builtin_bit_cast(float, u);
}

__device__ __forceinline__ f32x4 mfma_bf16(u16x8 a, u16x8 b, f32x4 c) {
  return __builtin_amdgcn_mfma_f32_16x16x32_bf16(
      __builtin_bit_cast(bf16x8, a), __builtin_bit_cast(bf16x8, b), c, 0, 0, 0);
}

// async global->LDS, 16 B per lane (dest must be wave-uniform base + lane*16)
__device__ __forceinline__ void gload16(u16* lds, const u16* g) {
  __builtin_amdgcn_global_load_lds(
      (const __attribute__((address_space(1))) void*)g,
      (__attribute__((address_space(3))) void*)lds, 16, 0, 0);
}

// ---------------------------------------------------------------------------
// Prep: fp32 -> bf16 convert (x), 8 elems/thread
// ---------------------------------------------------------------------------
__global__ __launch_bounds__(256) void cvt_bf16_kernel(
    const float* __restrict__ in, u16* __restrict__ out, int n8) {
  int i = blockIdx.x * 256 + threadIdx.x;
  if (i >= n8) return;
  const float4 f0 = *(const float4*)(in + i * 8);
  const float4 f1 = *(const float4*)(in + i * 8 + 4);
  u16x8 pk;
  pk[0] = f2bf(f0.x); pk[1] = f2bf(f0.y); pk[2] = f2bf(f0.z); pk[3] = f2bf(f0.w);
  pk[4] = f2bf(f1.x); pk[5] = f2bf(f1.y); pk[6] = f2bf(f1.z); pk[7] = f2bf(f1.w);
  *(u16x8*)(out + i * 8) = pk;
}

// ---------------------------------------------------------------------------
// Prep: W[K][N] fp32 -> Wt[N][K] bf16 (32x32 LDS tile transpose)
// ---------------------------------------------------------------------------
__global__ __launch_bounds__(256) void transpose_w_kernel(
    const float* __restrict__ W, u16* __restrict__ Wt, int K, int N) {
  __shared__ float tile[32][33];
  const int n0 = blockIdx.x * 32, k0 = blockIdx.y * 32;
  const int tx = threadIdx.x & 31, ty = threadIdx.x >> 5;
  #pragma unroll
  for (int yy = ty; yy < 32; yy += 8)
    tile[yy][tx] = W[(size_t)(k0 + yy) * N + n0 + tx];
  __syncthreads();
  #pragma unroll
  for (int yy = ty; yy < 32; yy += 8)
    Wt[(size_t)(n0 + yy) * K + k0 + tx] = f2bf(tile[tx][yy]);
}

// ---------------------------------------------------------------------------
// Bias table: tab[h][d] = in_band(bucket(d),h) ? pos_bias[bucket(d)][h] : -100
// ---------------------------------------------------------------------------
__global__ __launch_bounds__(256) void bias_tab_kernel(
    const float* __restrict__ pos_bias, float* __restrict__ tab) {
  int d = blockIdx.x * 256 + threadIdx.x;   // 0..2047
  if (d >= NSEQ) return;
  int bkt;
  if (d < 28) {
    bkt = d;
  } else {
    double t = log((double)d / 28.0) / log(2048.0 / 28.0) * 16.0;
    int ti = 28 + (int)t;
    bkt = ti < 43 ? ti : 43;
  }
  const int lo[8] = {38, 34, 28, 20, 13, 7, 3, 0};
  const int hi[8] = {44, 40, 35, 28, 21, 14, 9, 6};
  #pragma unroll
  for (int h = 0; h < HNUM; ++h) {
    bool inb = (bkt >= lo[h]) && (bkt < hi[h]);
    tab[h * NSEQ + d] = inb ? pos_bias[bkt * HNUM + h] : -100.0f;
  }
}

// ---------------------------------------------------------------------------
// m97-style bf16 GEMM: C[M,NCOLS] = Abf[M,512] @ Wt[NCOLS,512]^T + bias
// EPI 0: pack q/k (+kdelta, q*0.125), v TRANSPOSED (+vdelta) -> vbfT[b][h][d][n]
// EPI 1: sigmoid -> bf16 | EPI 2: fp32 out
// ---------------------------------------------------------------------------
template <int NCOLS, int EPI>
__global__ __launch_bounds__(256) void gemm_bf16(
    const u16* __restrict__ Abf, const u16* __restrict__ Wt,
    const float* __restrict__ bias,
    const float* __restrict__ kdelta, const float* __restrict__ vdelta,
    u16* __restrict__ qbf, u16* __restrict__ kbf, u16* __restrict__ vbfT,
    u16* __restrict__ outbf, float* __restrict__ outf) {
  __shared__ __align__(16) u16 As[128 * 32];
  __shared__ __align__(16) u16 Bs[128 * 32];

  const int m0 = blockIdx.y * 128;
  const int n0 = blockIdx.x * 128;
  const int tid = threadIdx.x;
  const int w = tid >> 6, l = tid & 63, li = l & 15, lg = l >> 4;
  const int wr = w >> 1, wc = w & 1;

  f32x4 acc[4][4];
  #pragma unroll
  for (int i = 0; i < 4; ++i)
    #pragma unroll
    for (int j = 0; j < 4; ++j) acc[i][j] = f32x4{0.f, 0.f, 0.f, 0.f};

  for (int kt = 0; kt < DMODEL / 32; ++kt) {
    #pragma unroll
    for (int i = 0; i < 2; ++i) {
      const int off = (i * 256 + tid) * 8;        // u16 units; dst linear
      const int row = off >> 5, col = off & 31;
      gload16(&As[off], Abf + (size_t)(m0 + row) * DMODEL + kt * 32 + col);
      gload16(&Bs[off], Wt + (size_t)(n0 + row) * DMODEL + kt * 32 + col);
    }
    __syncthreads();   // drains vmcnt -> LDS ready

    u16x8 af[4], bfr[4];
    #pragma unroll
    for (int mt = 0; mt < 4; ++mt)
      af[mt] = *(const u16x8*)&As[(wr * 64 + mt * 16 + li) * 32 + lg * 8];
    #pragma unroll
    for (int nt = 0; nt < 4; ++nt)
      bfr[nt] = *(const u16x8*)&Bs[(wc * 64 + nt * 16 + li) * 32 + lg * 8];
    #pragma unroll
    for (int mt = 0; mt < 4; ++mt)
      #pragma unroll
      for (int nt = 0; nt < 4; ++nt)
        acc[mt][nt] = mfma_bf16(af[mt], bfr[nt], acc[mt][nt]);
    __syncthreads();
  }

  // epilogue: row = m0+wr*64+mt*16+lg*4+r ; col = n0+wc*64+nt*16+li
  #pragma unroll
  for (int nt = 0; nt < 4; ++nt) {
    const int colg = n0 + wc * 64 + nt * 16 + li;
    const float bv = bias[colg];
    #pragma unroll
    for (int mt = 0; mt < 4; ++mt) {
      const int rowbase = m0 + wr * 64 + mt * 16 + lg * 4;
      if constexpr (EPI == 0) {
        const int which = colg >> 9;          // 0=q 1=k 2=v
        const int inner = colg & 511;
        const int hh = inner >> 6, hd = inner & 63;
        const int bb = rowbase >> 11, nn0 = rowbase & 2047;
        if (which == 2) {
          u16x4 pk;
          #pragma unroll
          for (int r = 0; r < 4; ++r) {
            const size_t idn =
                (((size_t)bb * HNUM + hh) * NSEQ + nn0 + r) * HDIM + hd;
            pk[r] = f2bf(acc[mt][nt][r] + bv + vdelta[idn]);
          }
          *(u16x4*)&vbfT[(((size_t)bb * HNUM + hh) * HDIM + hd) * NSEQ + nn0] =
              pk;
        } else {
          #pragma unroll
          for (int r = 0; r < 4; ++r) {
            const size_t idx =
                (((size_t)bb * HNUM + hh) * NSEQ + nn0 + r) * HDIM + hd;
            const float val = acc[mt][nt][r] + bv;
            if (which == 0) qbf[idx] = f2bf(val * 0.125f);
            else            kbf[idx] = f2bf(val + kdelta[idx]);
          }
        }
      } else {
        #pragma unroll
        for (int r = 0; r < 4; ++r) {
          const int rowg = rowbase + r;
          const float val = acc[mt][nt][r] + bv;
          if constexpr (EPI == 1)
            outbf[(size_t)rowg * NCOLS + colg] =
                f2bf(1.f / (1.f + __expf(-val)));
          else
            outf[(size_t)rowg * NCOLS + colg] = val;
        }
      }
    }
  }
}

// ---------------------------------------------------------------------------
// Flash attention, swapped-QK^T, banded KV windows, split-KV balanced chunks.
// Grid 1536: slot(12) x qt(32, descending) x b(4).
//   slots 0-3: h0 chunk 0..3 | 4-5: h1 chunk 0..1 | 6-11: h2..h7 direct.
// Split chunks write unnormalized partials (O bf16, m/l f32); combine_kernel
// merges. Direct heads apply gain+gate and write attn_out.
// ---------------------------------------------------------------------------
__global__ __launch_bounds__(256) void attn_kernel(
    const u16* __restrict__ qbf, const u16* __restrict__ kbf,
    const u16* __restrict__ vbfT, const float* __restrict__ bias_tab,
    const float* __restrict__ if_gain, const u16* __restrict__ gate,
    u16* __restrict__ attn_out, u16* __restrict__ partO,
    float* __restrict__ partM, float* __restrict__ partL) {
  __shared__ __align__(16) u16 Ks[64][LP];   // [kv][hd]
  __shared__ __align__(16) u16 Vt[64][LP];   // [hd][kv]
  __shared__ __align__(16) u16 Pl[4][16][LP];

  static const int DMINW[8] = {408, 139, 26, 18, 11, 5, 1, 0};
  static const int DMAXW[8] = {2049, 702, 185, 29, 22, 15, 10, 7};
  static const int DMINS[8] = {412, 143, 30, 22, 15, 9, 5, 2};
  static const int SH[12] = {0, 0, 0, 0, 1, 1, 2, 3, 4, 5, 6, 7};
  static const int SC[12] = {0, 1, 2, 3, 0, 1, 0, 0, 0, 0, 0, 0};
  static const int SN[12] = {4, 4, 4, 4, 2, 2, 1, 1, 1, 1, 1, 1};

  const int slot = blockIdx.x >> 7;
  const int rem = blockIdx.x & 127;
  const int qt = 31 - (rem >> 2);
  const int b = rem & 3;
  const int h = SH[slot], ch = SC[slot], nc = SN[slot];
  const int bh = b * HNUM + h;
  const int q0 = qt * 64;
  const int tid = threadIdx.x;
  const int w = tid >> 6, l = tid & 63, li = l & 15, lg = l >> 4;

  // Q fragment (B-operand): lane (li,lg) holds Q[q0+16w+li][8lg+e(+32)]
  const u16* qrow = qbf + ((size_t)bh * NSEQ + q0 + w * 16 + li) * HDIM;
  u16x8 qf0 = *(const u16x8*)(qrow + lg * 8);
  u16x8 qf1 = *(const u16x8*)(qrow + 32 + lg * 8);

  const bool pure = q0 >= DMINS[h];
  int kv_lo = 0, kv_hi = q0 + 64;
  if (pure) {
    int lo = q0 - DMAXW[h];
    kv_lo = (lo > 0 ? lo : 0) & ~63;
    kv_hi = q0 + 64 - DMINW[h];
  }
  const int t0 = kv_lo >> 6, t1 = (kv_hi - 1) >> 6;
  const int len = t1 - t0 + 1;
  const int ta = t0 + (len * ch) / nc;
  const int tb = t0 + (len * (ch + 1)) / nc - 1;

  const int srow = tid >> 2;          // 0..63 staging row
  const int scb = (tid & 3) << 4;     // 0,16,32,48 staging col block
  const float* btab = bias_tab + h * NSEQ;

  float mrun = -INFINITY, lrun = 0.f;
  f32x4 O[4] = {{0.f,0.f,0.f,0.f},{0.f,0.f,0.f,0.f},
                {0.f,0.f,0.f,0.f},{0.f,0.f,0.f,0.f}};

  for (int tt = ta; tt <= tb; ++tt) {
    const int kv0 = tt << 6;
    // ---- stage K [j][d] and V^T [d][j] (all-vector writes) ----
    {
      const size_t kbase = ((size_t)bh * NSEQ + kv0 + srow) * HDIM + scb;
      u16x8 k0 = *(const u16x8*)(kbf + kbase);
      u16x8 k1 = *(const u16x8*)(kbf + kbase + 8);
      const size_t vbase = ((size_t)bh * HDIM + srow) * NSEQ + kv0 + scb;
      u16x8 v0 = *(const u16x8*)(vbfT + vbase);
      u16x8 v1 = *(const u16x8*)(vbfT + vbase + 8);
      *(u16x8*)&Ks[srow][scb] = k0;
      *(u16x8*)&Ks[srow][scb + 8] = k1;
      *(u16x8*)&Vt[srow][scb] = v0;
      *(u16x8*)&Vt[srow][scb + 8] = v1;
    }
    __syncthreads();

    // ---- S^T = K Q^T : 4 j-tiles x (K=64 -> 2 mfma) ----
    f32x4 s[4];
    #pragma unroll
    for (int t = 0; t < 4; ++t) {
      u16x8 a0 = *(const u16x8*)&Ks[t * 16 + li][lg * 8];
      u16x8 a1 = *(const u16x8*)&Ks[t * 16 + li][32 + lg * 8];
      f32x4 acc = {0.f, 0.f, 0.f, 0.f};
      acc = mfma_bf16(a0, qf0, acc);
      acc = mfma_bf16(a1, qf1, acc);
      s[t] = acc;
    }

    // ---- bias + causal mask + online softmax (lane owns row i) ----
    const int D0 = (q0 + w * 16 + li) - kv0 - lg * 4;  // d = D0 - 16t - r
    float rm = -1e30f;
    #pragma unroll
    for (int t = 0; t < 4; ++t) {
      #pragma unroll
      for (int r = 0; r < 4; ++r) {
        int d = D0 - 16 * t - r;
        float sv = s[t][r];
        sv = (d >= 0) ? (sv + btab[d]) : -1e30f;
        s[t][r] = sv;
        rm = fmaxf(rm, sv);
      }
    }
    rm = fmaxf(rm, __shfl_xor(rm, 16, 64));
    rm = fmaxf(rm, __shfl_xor(rm, 32, 64));
    const float mn = fmaxf(mrun, rm);
    const float f = __expf(mrun - mn);
    mrun = mn;
    float ps = 0.f;
    #pragma unroll
    for (int t = 0; t < 4; ++t) {
      #pragma unroll
      for (int r = 0; r < 4; ++r) {
        float p = __expf(s[t][r] - mn);
        s[t][r] = p;
        ps += p;
      }
    }
    ps += __shfl_xor(ps, 16, 64);
    ps += __shfl_xor(ps, 32, 64);
    lrun = lrun * f + ps;

    #pragma unroll
    for (int t = 0; t < 4; ++t) {
      u16x4 pk;
      pk[0] = f2bf(s[t][0]); pk[1] = f2bf(s[t][1]);
      pk[2] = f2bf(s[t][2]); pk[3] = f2bf(s[t][3]);
      *(u16x4*)&Pl[w][li][t * 16 + lg * 4] = pk;
    }

    float fr[4];
    #pragma unroll
    for (int r = 0; r < 4; ++r) fr[r] = __shfl(f, lg * 4 + r, 64);
    #pragma unroll
    for (int dt = 0; dt < 4; ++dt) {
      O[dt][0] *= fr[0]; O[dt][1] *= fr[1];
      O[dt][2] *= fr[2]; O[dt][3] *= fr[3];
    }
    __syncthreads();

    #pragma unroll
    for (int ks = 0; ks < 2; ++ks) {
      u16x8 pA = *(const u16x8*)&Pl[w][li][ks * 32 + lg * 8];
      #pragma unroll
      for (int dt = 0; dt < 4; ++dt) {
        u16x8 vB = *(const u16x8*)&Vt[dt * 16 + li][ks * 32 + lg * 8];
        O[dt] = mfma_bf16(pA, vB, O[dt]);
      }
    }
    __syncthreads();
  }

  if (nc == 1) {
    // direct epilogue: normalize, gain, gate, write bf16 [B,N,D]
    const float gain = if_gain[h];
    float linv[4];
    #pragma unroll
    for (int r = 0; r < 4; ++r)
      linv[r] = gain / __shfl(lrun, lg * 4 + r, 64);
    #pragma unroll
    for (int r = 0; r < 4; ++r) {
      const int i = q0 + w * 16 + lg * 4 + r;
      const size_t base = ((size_t)b * NSEQ + i) * DMODEL + h * HDIM + li;
      #pragma unroll
      for (int dt = 0; dt < 4; ++dt) {
        const float g = bf2f(gate[base + dt * 16]);
        attn_out[base + dt * 16] = f2bf(O[dt][r] * linv[r] * g);
      }
    }
  } else {
    // partial: unnormalized O (bf16) + per-row m,l
    const int sbase = (b * 32 + qt) * 6 + slot;   // slot in 0..5 here
    #pragma unroll
    for (int r = 0; r < 4; ++r) {
      const int rl = w * 16 + lg * 4 + r;
      #pragma unroll
      for (int dt = 0; dt < 4; ++dt)
        partO[(size_t)sbase * 4096 + rl * 64 + dt * 16 + li] = f2bf(O[dt][r]);
    }
    if (lg == 0) {
      partM[sbase * 64 + w * 16 + li] = mrun;
      partL[sbase * 64 + w * 16 + li] = lrun;
    }
  }
}

// ---------------------------------------------------------------------------
// Combine split-KV partials for h0 (4 chunks) and h1 (2 chunks).
// Grid 128 = (b,qt); thread = (row 0..63, dgroup 0..3 of 16 d).
// ---------------------------------------------------------------------------
__global__ __launch_bounds__(256) void combine_kernel(
    const u16* __restrict__ partO, const float* __restrict__ partM,
    const float* __restrict__ partL, const float* __restrict__ if_gain,
    const u16* __restrict__ gate, u16* __restrict__ attn_out) {
  const int b = blockIdx.x & 3, qt = blockIdx.x >> 2;
  const int tid = threadIdx.x;
  const int row = tid >> 2, d0 = (tid & 3) << 4;

  #pragma unroll
  for (int hc = 0; hc < 2; ++hc) {
    const int nc = hc ? 2 : 4, s0 = hc ? 4 : 0;
    const int sbase = (b * 32 + qt) * 6 + s0;
    float m[4], wch[4];
    float M = -INFINITY;
    #pragma unroll
    for (int c = 0; c < 4; ++c) {
      m[c] = (c < nc) ? partM[(sbase + c) * 64 + row] : -INFINITY;
      M = fmaxf(M, m[c]);
    }
    float den = 0.f;
    #pragma unroll
    for (int c = 0; c < 4; ++c) {
      wch[c] = (c < nc) ? __expf(m[c] - M) : 0.f;
      if (c < nc) den += wch[c] * partL[(sbase + c) * 64 + row];
    }
    float num[16];
    #pragma unroll
    for (int j = 0; j < 16; ++j) num[j] = 0.f;
    #pragma unroll
    for (int c = 0; c < 4; ++c) {
      if (c < nc) {
        const u16* op = partO + (size_t)(sbase + c) * 4096 + row * 64 + d0;
        u16x8 o0 = *(const u16x8*)op;
        u16x8 o1 = *(const u16x8*)(op + 8);
        #pragma unroll
        for (int j = 0; j < 8; ++j) {
          num[j]     += wch[c] * bf2f(o0[j]);
          num[8 + j] += wch[c] * bf2f(o1[j]);
        }
      }
    }
    const float inv = if_gain[hc] / den;
    const size_t obase =
        ((size_t)b * NSEQ + qt * 64 + row) * DMODEL + hc * HDIM + d0;
    u16x8 g0 = *(const u16x8*)(gate + obase);
    u16x8 g1 = *(const u16x8*)(gate + obase + 8);
    u16x8 r0, r1;
    #pragma unroll
    for (int j = 0; j < 8; ++j) {
      r0[j] = f2bf(num[j] * inv * bf2f(g0[j]));
      r1[j] = f2bf(num[8 + j] * inv * bf2f(g1[j]));
    }
    *(u16x8*)(attn_out + obase) = r0;
    *(u16x8*)(attn_out + obase + 8) = r1;
  }
}

// ---------------------------------------------------------------------------
extern "C" void kernel_launch(void* const* d_in, const int* in_sizes, int n_in,
                              void* d_out, int out_size, void* d_ws,
                              size_t ws_size, hipStream_t stream) {
  const float* x       = (const float*)d_in[0];
  const float* k_delta = (const float*)d_in[1];
  const float* v_delta = (const float*)d_in[2];
  const float* qkv_w   = (const float*)d_in[3];
  const float* qkv_b   = (const float*)d_in[4];
  const float* gate_w  = (const float*)d_in[5];
  const float* gate_b  = (const float*)d_in[6];
  const float* out_w   = (const float*)d_in[7];
  const float* out_b   = (const float*)d_in[8];
  const float* pos_bias = (const float*)d_in[9];
  const float* if_gain  = (const float*)d_in[10];
  float* out = (float*)d_out;
  char* ws = (char*)d_ws;

  // workspace layout (bytes)
  u16*   xbf      = (u16*)(ws + 0);              //  8,388,608 (dead after GEMMs)
  u16*   qbf      = (u16*)(ws + 8388608);        //  8,388,608
  u16*   kbf      = (u16*)(ws + 16777216);       //  8,388,608
  u16*   vbfT     = (u16*)(ws + 25165824);       //  8,388,608
  u16*   gate_buf = (u16*)(ws + 33554432);       //  8,388,608
  u16*   attn_buf = (u16*)(ws + 41943040);       //  8,388,608
  u16*   qkv_wt   = (u16*)(ws + 50331648);       //  1,572,864
  u16*   gate_wt  = (u16*)(ws + 51904512);       //    524,288
  u16*   out_wt   = (u16*)(ws + 52428800);       //    524,288
  float* bias_tab = (float*)(ws + 52953088);     //     65,536
  // split-KV partials alias the dead xbf region (written by attn, read by
  // combine; xbf's last reader is the gate GEMM, strictly earlier in-stream)
  u16*   partO = (u16*)(ws + 0);                 //  6,291,456
  float* partM = (float*)(ws + 6291456);         //    196,608
  float* partL = (float*)(ws + 6488064);         //    196,608

  // prep
  cvt_bf16_kernel<<<dim3(2048), dim3(256), 0, stream>>>(
      x, xbf, BATCH * NSEQ * DMODEL / 8);
  transpose_w_kernel<<<dim3(48, 16), dim3(256), 0, stream>>>(
      qkv_w, qkv_wt, DMODEL, 3 * DMODEL);
  transpose_w_kernel<<<dim3(16, 16), dim3(256), 0, stream>>>(
      gate_w, gate_wt, DMODEL, DMODEL);
  transpose_w_kernel<<<dim3(16, 16), dim3(256), 0, stream>>>(
      out_w, out_wt, DMODEL, DMODEL);
  bias_tab_kernel<<<dim3(8), dim3(256), 0, stream>>>(pos_bias, bias_tab);

  // qkv GEMM + pack (v transposed)
  gemm_bf16<1536, 0><<<dim3(12, 64), dim3(256), 0, stream>>>(
      xbf, qkv_wt, qkv_b, k_delta, v_delta, qbf, kbf, vbfT, nullptr, nullptr);

  // gate GEMM -> sigmoid bf16
  gemm_bf16<512, 1><<<dim3(4, 64), dim3(256), 0, stream>>>(
      xbf, gate_wt, gate_b, nullptr, nullptr, nullptr, nullptr, nullptr,
      gate_buf, nullptr);

  // flash attention: split-KV balanced chunks
  attn_kernel<<<dim3(1536), dim3(256), 0, stream>>>(
      qbf, kbf, vbfT, bias_tab, if_gain, gate_buf, attn_buf,
      partO, partM, partL);

  // merge h0/h1 partials
  combine_kernel<<<dim3(128), dim3(256), 0, stream>>>(
      partO, partM, partL, if_gain, gate_buf, attn_buf);

  // final GEMM -> d_out (fp32)
  gemm_bf16<512, 2><<<dim3(4, 64), dim3(256), 0, stream>>>(
      attn_buf, out_wt, out_b, nullptr, nullptr, nullptr, nullptr, nullptr,
      nullptr, out);

  (void)in_sizes; (void)n_in; (void)out_size; (void)ws_size;
}